// Round 10
// baseline (2485.202 us; speedup 1.0000x reference)
//
#include <hip/hip_runtime.h>

#define Bq 64
#define Sq 32
#define VFq 512
#define IFq 256
#define Fq 768
#define Uq 768
#define UNFq 6
#define L2E 1.44269504088896340736f
typedef unsigned long long ull;
typedef __attribute__((ext_vector_type(2))) float f2;

template <int CTRL>
__device__ __forceinline__ float dpp_add(float x) {
  int t = __builtin_amdgcn_update_dpp(0, __builtin_bit_cast(int, x), CTRL, 0xF, 0xF, true);
  return x + __builtin_bit_cast(float, t);
}
template <int OFF>
__device__ __forceinline__ float swz_add(float x) {   // BitMode xor swizzle (within 32)
  int t = __builtin_amdgcn_ds_swizzle(__builtin_bit_cast(int, x), OFF);
  return x + __builtin_bit_cast(float, t);
}

// ---------------- K1: fold+transpose params, init misc ----------------
// P[u][v] = float4(-sigma*log2e, sigma*mu*log2e, w, w*erev)  (u = target, v = source)
__global__ __launch_bounds__(256) void k_prep(
    const float* __restrict__ smu, const float* __restrict__ ssig,
    const float* __restrict__ sw,  const float* __restrict__ ser,
    const float* __restrict__ rmu, const float* __restrict__ rsig,
    const float* __restrict__ rw,  const float* __restrict__ rer,
    const float* __restrict__ ts,
    float4* __restrict__ Ps, float4* __restrict__ Pr,
    float* __restrict__ iel, unsigned* __restrict__ flags)
{
  int bid = blockIdx.x, tid = threadIdx.x;
  if (bid < 1152) {
    int set = bid / 576, tile = bid % 576;
    int tv = tile / 24, tu = tile % 24;
    const float* Amu = set ? rmu : smu;
    const float* Asg = set ? rsig : ssig;
    const float* Aw  = set ? rw  : sw;
    const float* Aer = set ? rer : ser;
    float4* P = set ? Pr : Ps;
    __shared__ float4 tl[32][33];
    int cu = tid & 31, r0 = tid >> 5;            // 32 cols x 8 rows
    for (int rr = 0; rr < 32; rr += 8) {
      int v = tv*32 + r0 + rr, u = tu*32 + cu;
      int idx = v*Uq + u;                         // source-major input layout
      float sg = Asg[idx], m = Amu[idx], ww = Aw[idx], er = Aer[idx];
      tl[cu][r0+rr] = make_float4(-sg*L2E, sg*m*L2E, ww, ww*er); // transposed in LDS
    }
    __syncthreads();
    for (int rr = 0; rr < 32; rr += 8) {
      int u = tu*32 + r0 + rr, v = tv*32 + (tid & 31);
      P[u*Fq + v] = tl[r0+rr][tid & 31];          // coalesced write, [u][v]
    }
  } else {
    for (int i = tid; i < Bq*Sq; i += 256) {
      int b = i / Sq, t = i % Sq;
      iel[i] = (float)UNFq / (ts[b*(Sq+1)+t+1] - ts[b*(Sq+1)+t]); // 6/elapsed
    }
    for (int i = tid; i < 1024; i += 256) flags[i] = 0u;  // per-block phase flags
  }
}

// ---------------- K2: sensory synapse sums for all (b,t) ----------------
__global__ __launch_bounds__(768) void k_sensory(
    const float* __restrict__ fv, const float* __restrict__ fi,
    const float* __restrict__ iw, const float* __restrict__ ib,
    const float4* __restrict__ Ps,
    float* __restrict__ wns, float* __restrict__ wds)
{
  __shared__ float xs[16][Fq];
  __shared__ float scr[12][8][33];
  int tid = threadIdx.x;
  int bt_tile = blockIdx.x >> 6;                  // 128 tiles of 16 (b,t)
  int ut = blockIdx.x & 63;                       // 64 u-tiles of 12
  int u0 = ut * 12, bt0 = bt_tile * 16;
  {
    float wv = iw[tid], bv = ib[tid];
    for (int j = 0; j < 16; ++j) {
      int bt = bt0 + j, b = bt >> 5, t = bt & 31;
      float raw = (tid < VFq) ? fv[(b*Sq + t)*VFq + tid]
                              : fi[(b*Sq + t)*IFq + (tid - VFq)];
      xs[j][tid] = raw * wv + bv;
    }
  }
  __syncthreads();
  int w = tid >> 6, l = tid & 63;
  const float4* P = Ps + (u0 + w)*Fq;
  #pragma unroll
  for (int pass = 0; pass < 4; ++pass) {
    f2 acc[4];
    #pragma unroll
    for (int q = 0; q < 4; ++q) acc[q] = (f2){0.f, 0.f};
    for (int i = 0; i < 12; ++i) {
      int f = l + 64*i;
      float4 p = P[f];
      f2 pwz = (f2){p.w, p.z};                    // (w*erev, w) packed
      #pragma unroll
      for (int q = 0; q < 4; ++q) {
        float arg = fmaf(p.x, xs[4*pass + q][f], p.y);
        float e = __builtin_amdgcn_exp2f(arg);
        float r = __builtin_amdgcn_rcpf(1.0f + e);  // sigmoid
        acc[q] = __builtin_elementwise_fma(pwz, (f2){r, r}, acc[q]); // v_pk_fma_f32
      }
    }
    #pragma unroll
    for (int q = 0; q < 4; ++q) {
      float num = acc[q].x, den = acc[q].y;
      num = dpp_add<0xB1>(num); den = dpp_add<0xB1>(den);
      num = dpp_add<0x4E>(num); den = dpp_add<0x4E>(den);
      num = swz_add<0x101F>(num); den = swz_add<0x101F>(den);
      if ((l & 7) == 0) {
        int rep = l >> 3;
        scr[w][rep][4*pass + q] = num;
        scr[w][rep][16 + 4*pass + q] = den;
      }
    }
    __builtin_amdgcn_sched_barrier(0);
  }
  __syncthreads();
  if (tid < 192) {
    int u = tid >> 4, j = tid & 15;
    float nt = 0.f, dt = 0.f;
    #pragma unroll
    for (int rep = 0; rep < 8; ++rep) { nt += scr[u][rep][j]; dt += scr[u][rep][16+j]; }
    int bt = bt0 + j, b = bt >> 5, t = bt & 31;
    wns[(t*Bq + b)*Uq + (u0 + u)] = nt;
    wds[(t*Bq + b)*Uq + (u0 + u)] = dt;
  }
}

// ---------------- K3: recurrent unfolds (persistent, prefetch pipeline) --------
// 256 blocks = 4 groups(16 b) x 64 u-tiles(12 u), 1 block/CU, 12 waves.
// Wave w <-> target u = u0+w; full 768-v P-row in 48 VGPRs.
// R10 changes vs R9 (per half-step):
//   - acc via v_pk_fma_f32 (num,den packed; S0=(w*erev,w) adjacent in P float4)
//   - final reduction finished IN-WAVE: each wave reads back its own scr2 rows
//     (same-wave DS ordering, no barrier), xor8/xor16 swizzle + xor32 shfl,
//     lanes 0-7 run the ODE for (u=w, 8 j) and store vg/hout.
//   -> sync2, the serialized 96-thread tail, and swn/swd LDS staging deleted.
//      ONE __syncthreads per half-step (covers panel(hp) writes + store drain).
// Everything else (poll placement after pass0, gather loads landing during
// pass1, single-buffer vg + per-block flag ring) is R9-proven, unchanged.
// VGPR budget 84 (LDS<64K -> 6 w/EU RA target; attrs not honored R3/R4);
// scr2 offload keeps live set ~80. Spill tripwire: WRITE_SIZE (~47 MB good).
__global__ __launch_bounds__(768)
void k_recurrent(
    const float4* __restrict__ Pr,
    const float* __restrict__ wns, const float* __restrict__ wds,
    float* __restrict__ vg, const float* __restrict__ iel,
    unsigned* __restrict__ flags,
    const float* __restrict__ gleak, const float* __restrict__ vleak,
    const float* __restrict__ cm, const float* __restrict__ ow,
    const float* __restrict__ ob, float* __restrict__ hout)
{
  __shared__ float4 vvP[4][Uq];         // 48 KiB: panels 2h,2h+1 = half h's j-quads
  __shared__ float2 scr2[12][8][9];     // 6.75 KiB per-wave reduce scratch (+pad)
  __shared__ float sinv[16][Sq];        // 2 KiB
  int tid = threadIdx.x;
  int g = blockIdx.x >> 6;              // group 0..3 (16 batches each)
  int ut = blockIdx.x & 63;             // u-tile 0..63
  int u0 = ut*12, b0 = g*16;
  if (tid < 512) { int j = tid >> 5, t = tid & 31; sinv[j][t] = iel[(b0+j)*Sq + t]; }
  #pragma unroll
  for (int q = 0; q < 4; ++q) vvP[q][tid] = make_float4(0.f, 0.f, 0.f, 0.f);
  int w = tid >> 6, l = tid & 63;
  // wave-uniform per-u scalars in regs (no LDS arrays)
  float my_gl   = gleak[u0 + w];
  float my_glvl = my_gl * vleak[u0 + w];
  float my_cm   = cm[u0 + w];
  float my_ow   = ow[u0 + w];
  float my_ob   = ob[u0 + w];
  float4 Prg[12];                       // entire P-row slice in registers (48 VGPRs)
  #pragma unroll
  for (int i = 0; i < 12; ++i) Prg[i] = Pr[(u0 + w)*Uq + l + 64*i];
  __syncthreads();
  int jl = l & 7;                       // lane's j-within-half (used when l<8)
  for (int t = 0; t < Sq; ++t) {
    // per-t sensory sums for this wave's u, lane jl (valid on lanes 0-7)
    float wn0 = wns[(t*Bq + b0 + jl)*Uq + u0 + w];
    float wd0 = wds[(t*Bq + b0 + jl)*Uq + u0 + w];
    float wn1 = wns[(t*Bq + b0 + 8 + jl)*Uq + u0 + w];
    float wd1 = wds[(t*Bq + b0 + 8 + jl)*Uq + u0 + w];
    for (int k = 0; k < UNFq; ++k) {
      int p = t*UNFq + k;               // phase 0..191
      #pragma unroll
      for (int h = 0; h < 2; ++h) {
        int hp = 1 - h;
        // ---- pass 0: j-quad 0 of half h (panel 2h) ----
        {
          f2 acc[4];
          #pragma unroll
          for (int q = 0; q < 4; ++q) acc[q] = (f2){0.f, 0.f};
          #pragma unroll
          for (int i = 0; i < 12; ++i) {
            int v = l + 64*i;
            float4 pp = Prg[i];
            f2 pwz = (f2){pp.w, pp.z};
            float4 y = vvP[2*h][v];
            float r0 = __builtin_amdgcn_rcpf(1.0f + __builtin_amdgcn_exp2f(fmaf(pp.x, y.x, pp.y)));
            float r1 = __builtin_amdgcn_rcpf(1.0f + __builtin_amdgcn_exp2f(fmaf(pp.x, y.y, pp.y)));
            float r2 = __builtin_amdgcn_rcpf(1.0f + __builtin_amdgcn_exp2f(fmaf(pp.x, y.z, pp.y)));
            float r3 = __builtin_amdgcn_rcpf(1.0f + __builtin_amdgcn_exp2f(fmaf(pp.x, y.w, pp.y)));
            acc[0] = __builtin_elementwise_fma(pwz, (f2){r0, r0}, acc[0]);
            acc[1] = __builtin_elementwise_fma(pwz, (f2){r1, r1}, acc[1]);
            acc[2] = __builtin_elementwise_fma(pwz, (f2){r2, r2}, acc[2]);
            acc[3] = __builtin_elementwise_fma(pwz, (f2){r3, r3}, acc[3]);
          }
          #pragma unroll
          for (int q = 0; q < 4; ++q) {
            float num = acc[q].x, den = acc[q].y;
            num = dpp_add<0xB1>(num); den = dpp_add<0xB1>(den);
            num = dpp_add<0x4E>(num); den = dpp_add<0x4E>(den);
            num = swz_add<0x101F>(num); den = swz_add<0x101F>(den);
            if ((l & 7) == 0) scr2[w][l >> 3][q] = make_float2(num, den);
          }
        }
        __builtin_amdgcn_sched_barrier(0);
        // ---- poll (slack = pass0) + issue gather loads for half hp ----
        ull ga0 = 0, ga1 = 0, ga2 = 0, ga3 = 0;
        bool do_g = !(p == 0 && h == 0);
        if (do_g) {
          const unsigned* f = flags + hp*256 + g*64 + l;  // every wave polls
          unsigned tgt = (unsigned)(p + h);               // h=0: p, h=1: p+1
          while (true) {
            unsigned vf = __hip_atomic_load(f, __ATOMIC_RELAXED, __HIP_MEMORY_SCOPE_AGENT);
            if (__ballot(vf < tgt) == 0ull) break;
            __builtin_amdgcn_s_sleep(1);
          }
          const ull* src = (const ull*)(vg + (hp*4 + g)*Uq*8) + tid*4;
          ga0 = __hip_atomic_load(src + 0, __ATOMIC_RELAXED, __HIP_MEMORY_SCOPE_AGENT);
          ga1 = __hip_atomic_load(src + 1, __ATOMIC_RELAXED, __HIP_MEMORY_SCOPE_AGENT);
          ga2 = __hip_atomic_load(src + 2, __ATOMIC_RELAXED, __HIP_MEMORY_SCOPE_AGENT);
          ga3 = __hip_atomic_load(src + 3, __ATOMIC_RELAXED, __HIP_MEMORY_SCOPE_AGENT);
        }
        __builtin_amdgcn_sched_barrier(0);
        // ---- pass 1: j-quad 1 of half h (panel 2h+1; gather lands here) ----
        {
          f2 acc[4];
          #pragma unroll
          for (int q = 0; q < 4; ++q) acc[q] = (f2){0.f, 0.f};
          #pragma unroll
          for (int i = 0; i < 12; ++i) {
            int v = l + 64*i;
            float4 pp = Prg[i];
            f2 pwz = (f2){pp.w, pp.z};
            float4 y = vvP[2*h+1][v];
            float r0 = __builtin_amdgcn_rcpf(1.0f + __builtin_amdgcn_exp2f(fmaf(pp.x, y.x, pp.y)));
            float r1 = __builtin_amdgcn_rcpf(1.0f + __builtin_amdgcn_exp2f(fmaf(pp.x, y.y, pp.y)));
            float r2 = __builtin_amdgcn_rcpf(1.0f + __builtin_amdgcn_exp2f(fmaf(pp.x, y.z, pp.y)));
            float r3 = __builtin_amdgcn_rcpf(1.0f + __builtin_amdgcn_exp2f(fmaf(pp.x, y.w, pp.y)));
            acc[0] = __builtin_elementwise_fma(pwz, (f2){r0, r0}, acc[0]);
            acc[1] = __builtin_elementwise_fma(pwz, (f2){r1, r1}, acc[1]);
            acc[2] = __builtin_elementwise_fma(pwz, (f2){r2, r2}, acc[2]);
            acc[3] = __builtin_elementwise_fma(pwz, (f2){r3, r3}, acc[3]);
          }
          #pragma unroll
          for (int q = 0; q < 4; ++q) {
            float num = acc[q].x, den = acc[q].y;
            num = dpp_add<0xB1>(num); den = dpp_add<0xB1>(den);
            num = dpp_add<0x4E>(num); den = dpp_add<0x4E>(den);
            num = swz_add<0x101F>(num); den = swz_add<0x101F>(den);
            if ((l & 7) == 0) scr2[w][l >> 3][4 + q] = make_float2(num, den);
          }
        }
        // ---- write gathered state into the other half's panels ----
        if (do_g) {
          float2 t0 = __builtin_bit_cast(float2, ga0);
          float2 t1 = __builtin_bit_cast(float2, ga1);
          float2 t2 = __builtin_bit_cast(float2, ga2);
          float2 t3 = __builtin_bit_cast(float2, ga3);
          vvP[2*hp+0][tid] = make_float4(t0.x, t0.y, t1.x, t1.y);
          vvP[2*hp+1][tid] = make_float4(t2.x, t2.y, t3.x, t3.y);
        }
        // ---- in-wave finish: read back OWN scr2 (same-wave DS order) ----
        {
          float2 me = scr2[w][l >> 3][jl];   // lane l -> (rep=l>>3, j=l&7)
          float nn = me.x, dd = me.y;
          nn = swz_add<0x201F>(nn); dd = swz_add<0x201F>(dd);   // xor 8
          nn = swz_add<0x401F>(nn); dd = swz_add<0x401F>(dd);   // xor 16
          nn += __shfl_xor(nn, 32, 64);      dd += __shfl_xor(dd, 32, 64);
          if (l < 8) {                      // lane j: ODE for (u=u0+w, j)
            int jh = h*8 + jl;
            float nt = nn + (h ? wn1 : wn0);
            float dt = dd + (h ? wd1 : wd0);
            float cmt = my_cm * sinv[jh][t];
            float vold = ((const float*)&vvP[2*h + (jl >> 2)][u0 + w])[jl & 3];
            float vnew = (cmt*vold + my_glvl + nt)
                       * __builtin_amdgcn_rcpf(cmt + my_gl + dt + 1e-8f);
            __hip_atomic_store(&vg[(h*4 + g)*Uq*8 + (u0 + w)*8 + jl], vnew,
                               __ATOMIC_RELAXED, __HIP_MEMORY_SCOPE_AGENT);
            if (k == UNFq-1)
              hout[((b0 + jh)*Sq + t)*Uq + u0 + w] = fmaf(vnew, my_ow, my_ob);
          }
        }
        __builtin_amdgcn_s_waitcnt(0);  // drain vg stores (all waves)
        __syncthreads();                // single barrier: panels(hp) + drain
        if (tid == 0)                   // contention-free signal
          __hip_atomic_store(&flags[h*256 + g*64 + ut], (unsigned)(p + 1),
                             __ATOMIC_RELAXED, __HIP_MEMORY_SCOPE_AGENT);
      }
    }
  }
}

// ---------------- K4: regressor head ----------------
__global__ __launch_bounds__(128) void k_head(
    const float* __restrict__ hseq, const float* __restrict__ W1,
    const float* __restrict__ b1, const float* __restrict__ W2,
    const float* __restrict__ b2, float* __restrict__ pose)
{
  __shared__ float h[Uq];
  __shared__ float x1[128];
  int bt = blockIdx.x, tid = threadIdx.x;
  for (int j = 0; j < 6; ++j) h[tid + 128*j] = hseq[bt*Uq + tid + 128*j];
  __syncthreads();
  float acc = b1[tid];
  for (int f = 0; f < Uq; ++f) acc = fmaf(h[f], W1[f*128 + tid], acc);
  x1[tid] = acc > 0.f ? acc : 0.1f*acc;            // LeakyReLU(0.1); h0 == 0
  __syncthreads();
  if (tid < 6) {
    float a2 = b2[tid];
    #pragma unroll
    for (int c = 0; c < 128; ++c) a2 = fmaf(x1[c], W2[c*6 + tid], a2);
    pose[bt*6 + tid] = a2;
  }
}

extern "C" void kernel_launch(void* const* d_in, const int* in_sizes, int n_in,
                              void* d_out, int out_size, void* d_ws, size_t ws_size,
                              hipStream_t stream) {
  const float* fv   = (const float*)d_in[0];
  const float* fi   = (const float*)d_in[2];
  const float* ts   = (const float*)d_in[4];
  const float* iw   = (const float*)d_in[5];
  const float* ibb  = (const float*)d_in[6];
  const float* smu  = (const float*)d_in[7];
  const float* ssig = (const float*)d_in[8];
  const float* sw   = (const float*)d_in[9];
  const float* ser  = (const float*)d_in[10];
  const float* rmu  = (const float*)d_in[11];
  const float* rsig = (const float*)d_in[12];
  const float* rw   = (const float*)d_in[13];
  const float* rer  = (const float*)d_in[14];
  const float* gl   = (const float*)d_in[15];
  const float* vl   = (const float*)d_in[16];
  const float* cm   = (const float*)d_in[17];
  const float* ow   = (const float*)d_in[18];
  const float* ob   = (const float*)d_in[19];
  const float* W1   = (const float*)d_in[20];
  const float* b1   = (const float*)d_in[21];
  const float* W2   = (const float*)d_in[22];
  const float* b2   = (const float*)d_in[23];

  float* pose = (float*)d_out;                 // (B,1,S,6) = 12288 floats
  float* hseq = (float*)d_out + Bq*Sq*6;       // (B,S,U)   = 1572864 floats

  float* ws = (float*)d_ws;
  float4* Ps = (float4*)ws;                    // 2,359,296 floats
  float4* Pr = (float4*)(ws + 2359296);        // 2,359,296
  float* wns = ws + 4718592;                   // 1,572,864
  float* wds = ws + 6291456;                   // 1,572,864
  float* vg  = ws + 7864320;                   // 49,152 (2 half x 4 g x 768 u x 8 j)
  float* iel = ws + 7962624;                   // 2,048
  unsigned* flags = (unsigned*)(ws + 7964672); // 512 used (2 half x 4 g x 64)

  k_prep<<<1153, 256, 0, stream>>>(smu, ssig, sw, ser, rmu, rsig, rw, rer,
                                   ts, Ps, Pr, iel, flags);
  k_sensory<<<8192, 768, 0, stream>>>(fv, fi, iw, ibb, Ps, wns, wds);
  k_recurrent<<<256, 768, 0, stream>>>(Pr, wns, wds, vg, iel, flags,
                                       gl, vl, cm, ow, ob, hseq);
  k_head<<<2048, 128, 0, stream>>>(hseq, W1, b1, W2, b2, pose);
}

// Round 11
// 2366.068 us; speedup vs baseline: 1.0504x; 1.0504x over previous
//
#include <hip/hip_runtime.h>

#define Bq 64
#define Sq 32
#define VFq 512
#define IFq 256
#define Fq 768
#define Uq 768
#define UNFq 6
#define L2E 1.44269504088896340736f
typedef unsigned long long ull;
typedef __attribute__((ext_vector_type(2))) float f2;

template <int CTRL>
__device__ __forceinline__ float dpp_add(float x) {
  int t = __builtin_amdgcn_update_dpp(0, __builtin_bit_cast(int, x), CTRL, 0xF, 0xF, true);
  return x + __builtin_bit_cast(float, t);
}
template <int OFF>
__device__ __forceinline__ float swz_add(float x) {   // BitMode xor swizzle (within 32)
  int t = __builtin_amdgcn_ds_swizzle(__builtin_bit_cast(int, x), OFF);
  return x + __builtin_bit_cast(float, t);
}

// ---------------- K1: fold+transpose params, init misc ----------------
// P[u][v] = float4(-sigma*log2e, sigma*mu*log2e, w, w*erev)  (u = target, v = source)
__global__ __launch_bounds__(256) void k_prep(
    const float* __restrict__ smu, const float* __restrict__ ssig,
    const float* __restrict__ sw,  const float* __restrict__ ser,
    const float* __restrict__ rmu, const float* __restrict__ rsig,
    const float* __restrict__ rw,  const float* __restrict__ rer,
    const float* __restrict__ ts,
    float4* __restrict__ Ps, float4* __restrict__ Pr,
    float* __restrict__ iel, unsigned* __restrict__ flags)
{
  int bid = blockIdx.x, tid = threadIdx.x;
  if (bid < 1152) {
    int set = bid / 576, tile = bid % 576;
    int tv = tile / 24, tu = tile % 24;
    const float* Amu = set ? rmu : smu;
    const float* Asg = set ? rsig : ssig;
    const float* Aw  = set ? rw  : sw;
    const float* Aer = set ? rer : ser;
    float4* P = set ? Pr : Ps;
    __shared__ float4 tl[32][33];
    int cu = tid & 31, r0 = tid >> 5;            // 32 cols x 8 rows
    for (int rr = 0; rr < 32; rr += 8) {
      int v = tv*32 + r0 + rr, u = tu*32 + cu;
      int idx = v*Uq + u;                         // source-major input layout
      float sg = Asg[idx], m = Amu[idx], ww = Aw[idx], er = Aer[idx];
      tl[cu][r0+rr] = make_float4(-sg*L2E, sg*m*L2E, ww, ww*er); // transposed in LDS
    }
    __syncthreads();
    for (int rr = 0; rr < 32; rr += 8) {
      int u = tu*32 + r0 + rr, v = tv*32 + (tid & 31);
      P[u*Fq + v] = tl[r0+rr][tid & 31];          // coalesced write, [u][v]
    }
  } else {
    for (int i = tid; i < Bq*Sq; i += 256) {
      int b = i / Sq, t = i % Sq;
      iel[i] = (float)UNFq / (ts[b*(Sq+1)+t+1] - ts[b*(Sq+1)+t]); // 6/elapsed
    }
    for (int i = tid; i < 1024; i += 256) flags[i] = 0u;  // per-block phase flags
  }
}

// ---------------- K2: sensory synapse sums for all (b,t) ----------------
__global__ __launch_bounds__(768) void k_sensory(
    const float* __restrict__ fv, const float* __restrict__ fi,
    const float* __restrict__ iw, const float* __restrict__ ib,
    const float4* __restrict__ Ps,
    float* __restrict__ wns, float* __restrict__ wds)
{
  __shared__ float xs[16][Fq];
  __shared__ float scr[12][8][33];
  int tid = threadIdx.x;
  int bt_tile = blockIdx.x >> 6;                  // 128 tiles of 16 (b,t)
  int ut = blockIdx.x & 63;                       // 64 u-tiles of 12
  int u0 = ut * 12, bt0 = bt_tile * 16;
  {
    float wv = iw[tid], bv = ib[tid];
    for (int j = 0; j < 16; ++j) {
      int bt = bt0 + j, b = bt >> 5, t = bt & 31;
      float raw = (tid < VFq) ? fv[(b*Sq + t)*VFq + tid]
                              : fi[(b*Sq + t)*IFq + (tid - VFq)];
      xs[j][tid] = raw * wv + bv;
    }
  }
  __syncthreads();
  int w = tid >> 6, l = tid & 63;
  const float4* P = Ps + (u0 + w)*Fq;
  #pragma unroll
  for (int pass = 0; pass < 4; ++pass) {
    f2 acc[4];
    #pragma unroll
    for (int q = 0; q < 4; ++q) acc[q] = (f2){0.f, 0.f};
    for (int i = 0; i < 12; ++i) {
      int f = l + 64*i;
      float4 p = P[f];
      f2 pwz = (f2){p.w, p.z};                    // (w*erev, w) packed
      #pragma unroll
      for (int q = 0; q < 4; ++q) {
        float arg = fmaf(p.x, xs[4*pass + q][f], p.y);
        float e = __builtin_amdgcn_exp2f(arg);
        float r = __builtin_amdgcn_rcpf(1.0f + e);  // sigmoid
        acc[q] = __builtin_elementwise_fma(pwz, (f2){r, r}, acc[q]); // v_pk_fma_f32
      }
    }
    #pragma unroll
    for (int q = 0; q < 4; ++q) {
      float num = acc[q].x, den = acc[q].y;
      num = dpp_add<0xB1>(num); den = dpp_add<0xB1>(den);
      num = dpp_add<0x4E>(num); den = dpp_add<0x4E>(den);
      num = swz_add<0x101F>(num); den = swz_add<0x101F>(den);
      if ((l & 7) == 0) {
        int rep = l >> 3;
        scr[w][rep][4*pass + q] = num;
        scr[w][rep][16 + 4*pass + q] = den;
      }
    }
    __builtin_amdgcn_sched_barrier(0);
  }
  __syncthreads();
  if (tid < 192) {
    int u = tid >> 4, j = tid & 15;
    float nt = 0.f, dt = 0.f;
    #pragma unroll
    for (int rep = 0; rep < 8; ++rep) { nt += scr[u][rep][j]; dt += scr[u][rep][16+j]; }
    int bt = bt0 + j, b = bt >> 5, t = bt & 31;
    wns[(t*Bq + b)*Uq + (u0 + u)] = nt;
    wds[(t*Bq + b)*Uq + (u0 + u)] = dt;
  }
}

// ---------------- K3: recurrent unfolds (persistent, prefetch pipeline) --------
// 256 blocks = 4 groups(16 b) x 64 u-tiles(12 u), 1 block/CU, 12 waves.
// R11 = R9's proven skeleton (R10's in-wave finish REVERTED: it 5x'd LDS bank
// conflicts and regressed) + two orthogonal changes:
//  1. XCD-aware groups: g = blockIdx&3 (not >>6). Round-robin block->XCD puts
//     a barrier-group's 64 blocks on 2 XCDs ({g,g+4}) instead of 8 -> vg/flag
//     coherence RTT between 2 L2s.
//  2. Paired reciprocal: rcp(e0*e1) serves 2 sigmoids. Trans-pipe occupancy
//     (the serial floor: 384 ops x 8cyc x 3 waves = 3.84us/phase) -> 2.88us;
//     the 2 extra muls ride the slack VALU pipe. Range-safe: |arg|<~27 ->
//     pair product < 1e16.
// Per half-step X (half h): pass0(h) | poll X-1 + issue gather (no wait) |
// pass1(h) (gather lands) | panels(hp) write | sync | tail ODE | drain | sync
// | signal. Single-buffer vg (poll-before-store proof in R9).
// VGPR budget 84; scr2 offload keeps live ~80. Spill tripwire: WRITE_SIZE.
__global__ __launch_bounds__(768)
void k_recurrent(
    const float4* __restrict__ Pr,
    const float* __restrict__ wns, const float* __restrict__ wds,
    float* __restrict__ vg, const float* __restrict__ iel,
    unsigned* __restrict__ flags,
    const float* __restrict__ gleak, const float* __restrict__ vleak,
    const float* __restrict__ cm, const float* __restrict__ ow,
    const float* __restrict__ ob, float* __restrict__ hout)
{
  __shared__ float4 vvP[4][Uq];         // 48 KiB: panels 2h,2h+1 = half h's j-quads
  __shared__ float2 scr2[12][8][9];     // 6.75 KiB reduce scratch (one half)
  __shared__ float sinv[16][Sq];        // 2 KiB
  __shared__ float swn[2][96], swd[2][96];
  __shared__ float sgl[12], sglvl[12], scm[12], sow[12], sob[12];
  int tid = threadIdx.x;
  int g = blockIdx.x & 3;               // group 0..3 -> XCDs {g, g+4} (swizzle)
  int ut = blockIdx.x >> 2;             // u-tile 0..63
  int u0 = ut*12, b0 = g*16;
  if (tid < 512) { int j = tid >> 5, t = tid & 31; sinv[j][t] = iel[(b0+j)*Sq + t]; }
  if (tid < 12) {
    float gl0 = gleak[u0+tid];
    sgl[tid] = gl0; sglvl[tid] = gl0 * vleak[u0+tid];
    scm[tid] = cm[u0+tid]; sow[tid] = ow[u0+tid]; sob[tid] = ob[u0+tid];
  }
  #pragma unroll
  for (int q = 0; q < 4; ++q) vvP[q][tid] = make_float4(0.f, 0.f, 0.f, 0.f);
  int w = tid >> 6, l = tid & 63;
  float4 Prg[12];                       // entire P-row slice in registers (48 VGPRs)
  #pragma unroll
  for (int i = 0; i < 12; ++i) Prg[i] = Pr[(u0 + w)*Uq + l + 64*i];
  __syncthreads();
  int uu8 = tid >> 3, jv = tid & 7;     // tail mapping (tid<96)
  for (int t = 0; t < Sq; ++t) {
    if (tid < 96) {                     // stash this t's sensory sums in LDS
      swn[0][tid] = wns[(t*Bq + b0 + jv)*Uq + u0 + uu8];
      swd[0][tid] = wds[(t*Bq + b0 + jv)*Uq + u0 + uu8];
      swn[1][tid] = wns[(t*Bq + b0 + 8 + jv)*Uq + u0 + uu8];
      swd[1][tid] = wds[(t*Bq + b0 + 8 + jv)*Uq + u0 + uu8];
    }
    for (int k = 0; k < UNFq; ++k) {
      int p = t*UNFq + k;               // phase 0..191
      #pragma unroll
      for (int h = 0; h < 2; ++h) {
        int hp = 1 - h;
        float num0[4], den0[4], num1[4], den1[4];
        // ---- pass 0: j-quad 0 of half h (paired rcp) ----
        #pragma unroll
        for (int q = 0; q < 4; ++q) { num0[q] = 0.f; den0[q] = 0.f; }
        #pragma unroll
        for (int i = 0; i < 12; ++i) {
          int v = l + 64*i;
          float4 pp = Prg[i];
          float4 y = vvP[2*h][v];
          float e0 = 1.0f + __builtin_amdgcn_exp2f(fmaf(pp.x, y.x, pp.y));
          float e1 = 1.0f + __builtin_amdgcn_exp2f(fmaf(pp.x, y.y, pp.y));
          float e2 = 1.0f + __builtin_amdgcn_exp2f(fmaf(pp.x, y.z, pp.y));
          float e3 = 1.0f + __builtin_amdgcn_exp2f(fmaf(pp.x, y.w, pp.y));
          float r01 = __builtin_amdgcn_rcpf(e0 * e1);
          float r23 = __builtin_amdgcn_rcpf(e2 * e3);
          float s0 = r01 * e1, s1 = r01 * e0;
          float s2 = r23 * e3, s3 = r23 * e2;
          den0[0] = fmaf(pp.z, s0, den0[0]); num0[0] = fmaf(pp.w, s0, num0[0]);
          den0[1] = fmaf(pp.z, s1, den0[1]); num0[1] = fmaf(pp.w, s1, num0[1]);
          den0[2] = fmaf(pp.z, s2, den0[2]); num0[2] = fmaf(pp.w, s2, num0[2]);
          den0[3] = fmaf(pp.z, s3, den0[3]); num0[3] = fmaf(pp.w, s3, num0[3]);
        }
        #pragma unroll
        for (int q = 0; q < 4; ++q) {
          num0[q] = dpp_add<0xB1>(num0[q]); den0[q] = dpp_add<0xB1>(den0[q]);
          num0[q] = dpp_add<0x4E>(num0[q]); den0[q] = dpp_add<0x4E>(den0[q]);
          num0[q] = swz_add<0x101F>(num0[q]); den0[q] = swz_add<0x101F>(den0[q]);
        }
        if ((l & 7) == 0) {
          int r = l >> 3;
          #pragma unroll
          for (int q = 0; q < 4; ++q) scr2[w][r][q] = make_float2(num0[q], den0[q]);
        }
        __builtin_amdgcn_sched_barrier(0);
        // ---- poll (slack = pass0) + issue gather loads for half hp ----
        ull ga0 = 0, ga1 = 0, ga2 = 0, ga3 = 0;
        bool do_g = !(p == 0 && h == 0);
        if (do_g) {
          const unsigned* f = flags + hp*256 + g*64 + l;  // every wave polls
          unsigned tgt = (unsigned)(p + h);               // h=0: p, h=1: p+1
          while (true) {
            unsigned vf = __hip_atomic_load(f, __ATOMIC_RELAXED, __HIP_MEMORY_SCOPE_AGENT);
            if (__ballot(vf < tgt) == 0ull) break;
            __builtin_amdgcn_s_sleep(1);
          }
          const ull* src = (const ull*)(vg + (hp*4 + g)*Uq*8) + tid*4;
          ga0 = __hip_atomic_load(src + 0, __ATOMIC_RELAXED, __HIP_MEMORY_SCOPE_AGENT);
          ga1 = __hip_atomic_load(src + 1, __ATOMIC_RELAXED, __HIP_MEMORY_SCOPE_AGENT);
          ga2 = __hip_atomic_load(src + 2, __ATOMIC_RELAXED, __HIP_MEMORY_SCOPE_AGENT);
          ga3 = __hip_atomic_load(src + 3, __ATOMIC_RELAXED, __HIP_MEMORY_SCOPE_AGENT);
        }
        __builtin_amdgcn_sched_barrier(0);
        // ---- pass 1: j-quad 1 of half h (gather loads land here) ----
        #pragma unroll
        for (int q = 0; q < 4; ++q) { num1[q] = 0.f; den1[q] = 0.f; }
        #pragma unroll
        for (int i = 0; i < 12; ++i) {
          int v = l + 64*i;
          float4 pp = Prg[i];
          float4 y = vvP[2*h+1][v];
          float e0 = 1.0f + __builtin_amdgcn_exp2f(fmaf(pp.x, y.x, pp.y));
          float e1 = 1.0f + __builtin_amdgcn_exp2f(fmaf(pp.x, y.y, pp.y));
          float e2 = 1.0f + __builtin_amdgcn_exp2f(fmaf(pp.x, y.z, pp.y));
          float e3 = 1.0f + __builtin_amdgcn_exp2f(fmaf(pp.x, y.w, pp.y));
          float r01 = __builtin_amdgcn_rcpf(e0 * e1);
          float r23 = __builtin_amdgcn_rcpf(e2 * e3);
          float s0 = r01 * e1, s1 = r01 * e0;
          float s2 = r23 * e3, s3 = r23 * e2;
          den1[0] = fmaf(pp.z, s0, den1[0]); num1[0] = fmaf(pp.w, s0, num1[0]);
          den1[1] = fmaf(pp.z, s1, den1[1]); num1[1] = fmaf(pp.w, s1, num1[1]);
          den1[2] = fmaf(pp.z, s2, den1[2]); num1[2] = fmaf(pp.w, s2, num1[2]);
          den1[3] = fmaf(pp.z, s3, den1[3]); num1[3] = fmaf(pp.w, s3, num1[3]);
        }
        #pragma unroll
        for (int q = 0; q < 4; ++q) {
          num1[q] = dpp_add<0xB1>(num1[q]); den1[q] = dpp_add<0xB1>(den1[q]);
          num1[q] = dpp_add<0x4E>(num1[q]); den1[q] = dpp_add<0x4E>(den1[q]);
          num1[q] = swz_add<0x101F>(num1[q]); den1[q] = swz_add<0x101F>(den1[q]);
        }
        if ((l & 7) == 0) {
          int r = l >> 3;
          #pragma unroll
          for (int q = 0; q < 4; ++q) scr2[w][r][4+q] = make_float2(num1[q], den1[q]);
        }
        // ---- write gathered state into the other half's panels ----
        if (do_g) {
          float2 t0 = __builtin_bit_cast(float2, ga0);
          float2 t1 = __builtin_bit_cast(float2, ga1);
          float2 t2 = __builtin_bit_cast(float2, ga2);
          float2 t3 = __builtin_bit_cast(float2, ga3);
          vvP[2*hp+0][tid] = make_float4(t0.x, t0.y, t1.x, t1.y);
          vvP[2*hp+1][tid] = make_float4(t2.x, t2.y, t3.x, t3.y);
        }
        __syncthreads();                // [sync2] scr2 + panels(hp) ready
        // ---- tail: ODE for (12u x 8j) of half h ----
        if (tid < 96) {
          float nt = swn[h][tid], dt = swd[h][tid];
          #pragma unroll
          for (int r = 0; r < 8; ++r) { float2 s = scr2[uu8][r][jv]; nt += s.x; dt += s.y; }
          int jh = h*8 + jv;
          float cmt = scm[uu8] * sinv[jh][t];
          const float* vrow = (const float*)&vvP[2*h + (jv >> 2)][u0 + uu8];
          float vold = vrow[jv & 3];
          float vnew = (cmt*vold + sglvl[uu8] + nt)
                     * __builtin_amdgcn_rcpf(cmt + sgl[uu8] + dt + 1e-8f);
          __hip_atomic_store(&vg[(h*4 + g)*Uq*8 + (u0 + uu8)*8 + jv], vnew,
                             __ATOMIC_RELAXED, __HIP_MEMORY_SCOPE_AGENT);
          if (k == UNFq-1)
            hout[((b0 + jh)*Sq + t)*Uq + u0 + uu8] = fmaf(vnew, sow[uu8], sob[uu8]);
        }
        __builtin_amdgcn_s_waitcnt(0);  // drain tail stores (others: no-op)
        __syncthreads();                // [sync3] state globally visible
        if (tid == 0)                   // contention-free signal
          __hip_atomic_store(&flags[h*256 + g*64 + ut], (unsigned)(p + 1),
                             __ATOMIC_RELAXED, __HIP_MEMORY_SCOPE_AGENT);
      }
    }
  }
}

// ---------------- K4: regressor head ----------------
__global__ __launch_bounds__(128) void k_head(
    const float* __restrict__ hseq, const float* __restrict__ W1,
    const float* __restrict__ b1, const float* __restrict__ W2,
    const float* __restrict__ b2, float* __restrict__ pose)
{
  __shared__ float h[Uq];
  __shared__ float x1[128];
  int bt = blockIdx.x, tid = threadIdx.x;
  for (int j = 0; j < 6; ++j) h[tid + 128*j] = hseq[bt*Uq + tid + 128*j];
  __syncthreads();
  float acc = b1[tid];
  for (int f = 0; f < Uq; ++f) acc = fmaf(h[f], W1[f*128 + tid], acc);
  x1[tid] = acc > 0.f ? acc : 0.1f*acc;            // LeakyReLU(0.1); h0 == 0
  __syncthreads();
  if (tid < 6) {
    float a2 = b2[tid];
    #pragma unroll
    for (int c = 0; c < 128; ++c) a2 = fmaf(x1[c], W2[c*6 + tid], a2);
    pose[bt*6 + tid] = a2;
  }
}

extern "C" void kernel_launch(void* const* d_in, const int* in_sizes, int n_in,
                              void* d_out, int out_size, void* d_ws, size_t ws_size,
                              hipStream_t stream) {
  const float* fv   = (const float*)d_in[0];
  const float* fi   = (const float*)d_in[2];
  const float* ts   = (const float*)d_in[4];
  const float* iw   = (const float*)d_in[5];
  const float* ibb  = (const float*)d_in[6];
  const float* smu  = (const float*)d_in[7];
  const float* ssig = (const float*)d_in[8];
  const float* sw   = (const float*)d_in[9];
  const float* ser  = (const float*)d_in[10];
  const float* rmu  = (const float*)d_in[11];
  const float* rsig = (const float*)d_in[12];
  const float* rw   = (const float*)d_in[13];
  const float* rer  = (const float*)d_in[14];
  const float* gl   = (const float*)d_in[15];
  const float* vl   = (const float*)d_in[16];
  const float* cm   = (const float*)d_in[17];
  const float* ow   = (const float*)d_in[18];
  const float* ob   = (const float*)d_in[19];
  const float* W1   = (const float*)d_in[20];
  const float* b1   = (const float*)d_in[21];
  const float* W2   = (const float*)d_in[22];
  const float* b2   = (const float*)d_in[23];

  float* pose = (float*)d_out;                 // (B,1,S,6) = 12288 floats
  float* hseq = (float*)d_out + Bq*Sq*6;       // (B,S,U)   = 1572864 floats

  float* ws = (float*)d_ws;
  float4* Ps = (float4*)ws;                    // 2,359,296 floats
  float4* Pr = (float4*)(ws + 2359296);        // 2,359,296
  float* wns = ws + 4718592;                   // 1,572,864
  float* wds = ws + 6291456;                   // 1,572,864
  float* vg  = ws + 7864320;                   // 49,152 (2 half x 4 g x 768 u x 8 j)
  float* iel = ws + 7962624;                   // 2,048
  unsigned* flags = (unsigned*)(ws + 7964672); // 512 used (2 half x 4 g x 64)

  k_prep<<<1153, 256, 0, stream>>>(smu, ssig, sw, ser, rmu, rsig, rw, rer,
                                   ts, Ps, Pr, iel, flags);
  k_sensory<<<8192, 768, 0, stream>>>(fv, fi, iw, ibb, Ps, wns, wds);
  k_recurrent<<<256, 768, 0, stream>>>(Pr, wns, wds, vg, iel, flags,
                                       gl, vl, cm, ow, ob, hseq);
  k_head<<<2048, 128, 0, stream>>>(hseq, W1, b1, W2, b2, pose);
}